// Round 1
// baseline (468.788 us; speedup 1.0000x reference)
//
#include <hip/hip_runtime.h>
#include <hip/hip_bf16.h>

using short8 = __attribute__((ext_vector_type(8))) short;
using f32x4  = __attribute__((ext_vector_type(4))) float;

#define DDIM 512
#define NROWS 1024
#define CCLS 100000

__device__ inline unsigned short f2bf(float f) {
    unsigned int u = __float_as_uint(f);
    u += 0x7FFFu + ((u >> 16) & 1u);   // round-to-nearest-even
    return (unsigned short)(u >> 16);
}

// ---------------- kernel 1: normalize x rows -> bf16 ----------------
__global__ __launch_bounds__(256) void norm_x(const float* __restrict__ x,
                                              unsigned short* __restrict__ xn) {
    const int row = blockIdx.x;
    const int tid = threadIdx.x;
    float2 v = *(const float2*)(x + (size_t)row * DDIM + tid * 2);
    float ss = v.x * v.x + v.y * v.y;
#pragma unroll
    for (int m = 1; m < 64; m <<= 1) ss += __shfl_xor(ss, m);
    __shared__ float wsum[4];
    if ((tid & 63) == 0) wsum[tid >> 6] = ss;
    __syncthreads();
    float inv = 1.0f / sqrtf(wsum[0] + wsum[1] + wsum[2] + wsum[3]);
    unsigned int packed = (unsigned int)f2bf(v.x * inv) |
                          ((unsigned int)f2bf(v.y * inv) << 16);
    ((unsigned int*)xn)[(size_t)row * (DDIM / 2) + tid] = packed;
}

// ---------------- kernel 2: per-row inverse norm of W ----------------
__global__ __launch_bounds__(256) void norm_w(const float* __restrict__ W,
                                              float* __restrict__ winv) {
    const int row = blockIdx.x * 4 + (threadIdx.x >> 6);
    const int lane = threadIdx.x & 63;
    const float4* p = (const float4*)(W + (size_t)row * DDIM + lane * 8);
    float4 a = p[0], b = p[1];
    float ss = a.x*a.x + a.y*a.y + a.z*a.z + a.w*a.w
             + b.x*b.x + b.y*b.y + b.z*b.z + b.w*b.w;
#pragma unroll
    for (int m = 1; m < 64; m <<= 1) ss += __shfl_xor(ss, m);
    if (lane == 0) winv[row] = 1.0f / sqrtf(ss);
}

// ---------------- kernel 3: fused GEMM + exp-rowsum + target capture ----------------
// tile: BM=128 (samples) x BN=128 (classes), BK=64. 4 waves (2x2), each wave 64x64.
__global__ __launch_bounds__(256, 2) void arc_gemm(
    const unsigned short* __restrict__ xn,   // [1024][512] bf16
    const float* __restrict__ W,             // [C][512] f32 (raw)
    const float* __restrict__ winv,          // [C]
    const int* __restrict__ labels,          // [1024]
    float* __restrict__ rowsum,              // [1024] (pre-zeroed)
    float* __restrict__ tcos)                // [1024]
{
    __shared__ unsigned short lsB[128 * 64]; // 16 KB, XOR-swizzled
    __shared__ float lrow[128];
    __shared__ int   llab[128];

    const int tid  = threadIdx.x;
    const int lane = tid & 63;
    const int wid  = tid >> 6;
    const int wr   = wid >> 1, wc = wid & 1;
    const int m0   = blockIdx.x * 128;
    const int c0   = blockIdx.y * 128;

    if (tid < 128) { lrow[tid] = 0.0f; llab[tid] = labels[m0 + tid]; }

    f32x4 acc[4][4];
#pragma unroll
    for (int i = 0; i < 4; ++i)
#pragma unroll
        for (int j = 0; j < 4; ++j) acc[i][j] = (f32x4)(0.0f);

    // per-lane A base: A-frag layout: row = lane&15, k = (lane>>4)*8 + v (8 contiguous)
    const unsigned short* aBase =
        xn + (size_t)(m0 + wr * 64 + (lane & 15)) * DDIM + ((lane >> 4) * 8);

    for (int k0 = 0; k0 < DDIM; k0 += 64) {
        __syncthreads();
        // stage B: 128 classes x 64 k, f32 -> bf16, swizzled rows
#pragma unroll
        for (int it = 0; it < 8; ++it) {
            int idx  = it * 256 + tid;
            int brow = idx >> 4;        // class row in tile
            int ch   = idx & 15;        // 4-float chunk along k
            int c    = c0 + brow;
            float4 v;
            if (c < CCLS) v = *(const float4*)(W + (size_t)c * DDIM + k0 + ch * 4);
            else          v = make_float4(0.f, 0.f, 0.f, 0.f);
            unsigned int lo = (unsigned int)f2bf(v.x) | ((unsigned int)f2bf(v.y) << 16);
            unsigned int hi = (unsigned int)f2bf(v.z) | ((unsigned int)f2bf(v.w) << 16);
            int pcol = (ch * 8) ^ ((brow & 7) << 4);   // swizzled byte offset in row
            *(uint2*)((char*)lsB + brow * 128 + pcol) = make_uint2(lo, hi);
        }
        __syncthreads();

#pragma unroll
        for (int ks = 0; ks < 2; ++ks) {
            short8 af[4], bg[4];
#pragma unroll
            for (int i = 0; i < 4; ++i)
                af[i] = *(const short8*)(aBase + (size_t)i * 16 * DDIM + k0 + ks * 32);
            const int kb = ks * 64 + (lane >> 4) * 16;  // byte offset of k-chunk in row
#pragma unroll
            for (int j = 0; j < 4; ++j) {
                int row = wc * 64 + j * 16 + (lane & 15);
                int cb  = kb ^ ((row & 7) << 4);
                bg[j] = *(const short8*)((const char*)lsB + row * 128 + cb);
            }
#pragma unroll
            for (int i = 0; i < 4; ++i)
#pragma unroll
                for (int j = 0; j < 4; ++j)
                    acc[i][j] = __builtin_amdgcn_mfma_f32_16x16x32_bf16(
                        af[i], bg[j], acc[i][j], 0, 0, 0);
        }
    }
    __syncthreads();

    // epilogue: cos = acc * winv[c]; e = exp(64 cos); row-reduce; capture target cos
    float wv[4]; int cok[4], colj[4];
#pragma unroll
    for (int j = 0; j < 4; ++j) {
        int c = c0 + wc * 64 + j * 16 + (lane & 15);
        colj[j] = c;
        cok[j]  = (c < CCLS) ? 1 : 0;
        wv[j]   = cok[j] ? winv[c] : 0.0f;
    }
#pragma unroll
    for (int i = 0; i < 4; ++i) {
#pragma unroll
        for (int v = 0; v < 4; ++v) {
            const int rl  = wr * 64 + i * 16 + (lane >> 4) * 4 + v;  // C/D: row=(l>>4)*4+v
            const int lab = llab[rl];
            float s = 0.0f;
#pragma unroll
            for (int j = 0; j < 4; ++j) {
                if (cok[j]) {
                    float cv = acc[i][j][v] * wv[j];
                    float e  = __expf(64.0f * cv);
                    s += e;
                    if (colj[j] == lab) tcos[m0 + rl] = cv;
                }
            }
            s += __shfl_xor(s, 1);
            s += __shfl_xor(s, 2);
            s += __shfl_xor(s, 4);
            s += __shfl_xor(s, 8);
            if ((lane & 15) == 0) atomicAdd(&lrow[rl], s);
        }
    }
    __syncthreads();
    if (tid < 128) atomicAdd(&rowsum[m0 + tid], lrow[tid]);
}

// ---------------- kernel 4: final loss ----------------
__global__ __launch_bounds__(256) void arc_final(const float* __restrict__ rowsum,
                                                 const float* __restrict__ tcos,
                                                 float* __restrict__ out) {
    const int tid = threadIdx.x;
    const float cosM = 0.87758256189037271612f;  // cos(0.5)
    const float sinM = 0.47942553860420300027f;  // sin(0.5)
    float L = 0.0f;
    for (int n = tid; n < NROWS; n += 256) {
        float tc  = tcos[n];
        float tcl = fminf(fmaxf(tc, -1.0f + 1e-7f), 1.0f - 1e-7f);
        float num = 64.0f * (tcl * cosM - sinM * sqrtf(fmaxf(0.0f, 1.0f - tcl * tcl)));
        float den = __expf(num) + rowsum[n] - __expf(64.0f * tc);
        L += num - logf(den);
    }
    __shared__ float red[256];
    red[tid] = L;
    __syncthreads();
    for (int s = 128; s > 0; s >>= 1) {
        if (tid < s) red[tid] += red[tid + s];
        __syncthreads();
    }
    if (tid == 0) out[0] = -(red[0] / (float)NROWS);
}

// ---------------- launch ----------------
extern "C" void kernel_launch(void* const* d_in, const int* in_sizes, int n_in,
                              void* d_out, int out_size, void* d_ws, size_t ws_size,
                              hipStream_t stream) {
    const float* x      = (const float*)d_in[0];
    const float* W      = (const float*)d_in[1];
    const int*   labels = (const int*)d_in[2];
    float* out = (float*)d_out;
    char*  ws  = (char*)d_ws;

    unsigned short* xn   = (unsigned short*)(ws);                 // 1,048,576 B
    float* winv          = (float*)(ws + 1048576);                // 400,000 B
    float* rowsum        = (float*)(ws + 1048576 + 400000);       // 4,096 B
    float* tcos          = (float*)(ws + 1048576 + 400000 + 4096);// 4,096 B

    hipMemsetAsync(rowsum, 0, NROWS * sizeof(float), stream);

    norm_x<<<NROWS, 256, 0, stream>>>(x, xn);
    norm_w<<<CCLS / 4, 256, 0, stream>>>(W, winv);

    dim3 grid(NROWS / 128, (CCLS + 127) / 128);  // (8, 782) — m fastest for W L2 reuse
    arc_gemm<<<grid, 256, 0, stream>>>(xn, W, winv, labels, rowsum, tcos);

    arc_final<<<1, 256, 0, stream>>>(rowsum, tcos, out);
}